// Round 1
// baseline (1289.457 us; speedup 1.0000x reference)
//
#include <hip/hip_runtime.h>
#include <stdint.h>

// Problem constants (NemotronHMOE)
#define H      2048
#define LATD   1024
#define INTERD 1024
#define NE     32
#define NG     4
#define NTOPK  8
#define SINTER 4096
#define TTOK   2048          // B*S tokens
#define RSCALE 2.5f
#define TKROWS (TTOK*NTOPK)  // 16384 gathered rows

typedef __attribute__((ext_vector_type(8))) short bf16x8;
typedef __attribute__((ext_vector_type(4))) float f32x4;

typedef const void GVoid __attribute__((address_space(1)));
typedef void LVoid __attribute__((address_space(3)));

__device__ __forceinline__ float b2f(unsigned short u) {
    union { float f; unsigned u; } x; x.u = ((unsigned)u) << 16; return x.f;
}
__device__ __forceinline__ unsigned short f2b(float f) {  // round-to-nearest-even
    union { float f; unsigned u; } x; x.f = f;
    unsigned r = x.u + 0x7FFF + ((x.u >> 16) & 1);
    return (unsigned short)(r >> 16);
}

// ---------------- fp32 -> bf16 bulk convert ----------------
__global__ __launch_bounds__(256) void cvt_f32_bf16(const float* __restrict__ in,
                                                    unsigned short* __restrict__ out,
                                                    long n4) {
    long stride = (long)gridDim.x * 256;
    for (long i = (long)blockIdx.x * 256 + threadIdx.x; i < n4; i += stride) {
        float4 v = ((const float4*)in)[i];
        ushort4 o;
        o.x = f2b(v.x); o.y = f2b(v.y); o.z = f2b(v.z); o.w = f2b(v.w);
        ((ushort4*)out)[i] = o;
    }
}

// ---------------- gate + routing (exact fp32) ----------------
// One block per token: 4 waves x 8 experts dot-products, then thread 0 does
// the (tiny, E=32) noaux_tc group top-k selection exactly as the reference.
__global__ __launch_bounds__(256) void gate_route(const float* __restrict__ x,
                                                  const float* __restrict__ gw,
                                                  const float* __restrict__ gb,
                                                  int* __restrict__ counts,
                                                  int* __restrict__ tl_tok,
                                                  float* __restrict__ tl_w) {
    __shared__ float xs[H];
    __shared__ float lg[NE];
    int t = blockIdx.x;
    const float4* xp = (const float4*)(x + (size_t)t * H);
    for (int i = threadIdx.x; i < H / 4; i += 256) ((float4*)xs)[i] = xp[i];
    __syncthreads();
    int wid = threadIdx.x >> 6, lane = threadIdx.x & 63;
    #pragma unroll
    for (int ei = 0; ei < 8; ++ei) {
        int e = wid * 8 + ei;
        const float* w = gw + (size_t)e * H;
        float s = 0.f;
        for (int i = lane; i < H; i += 64) s += xs[i] * w[i];
        #pragma unroll
        for (int off = 32; off; off >>= 1) s += __shfl_xor(s, off);
        if (lane == 0) lg[e] = s;
    }
    __syncthreads();
    if (threadIdx.x == 0) {
        float sc[NE], sb[NE];
        for (int e = 0; e < NE; ++e) {
            sc[e] = 1.f / (1.f + expf(-lg[e]));   // sigmoid score
            sb[e] = sc[e] + gb[e];                // bias only affects selection
        }
        float gsc[NG];
        for (int g = 0; g < NG; ++g) {            // sum of top-2 per group
            float m1 = -1e30f, m2 = -1e30f;
            for (int i = 0; i < 8; ++i) {
                float v = sb[g * 8 + i];
                if (v > m1) { m2 = m1; m1 = v; } else if (v > m2) m2 = v;
            }
            gsc[g] = m1 + m2;
        }
        int g1 = 0;
        for (int g = 1; g < NG; ++g) if (gsc[g] > gsc[g1]) g1 = g;
        int g2 = -1;
        for (int g = 0; g < NG; ++g) { if (g == g1) continue; if (g2 < 0 || gsc[g] > gsc[g2]) g2 = g; }
        unsigned am = (0xFFu << (g1 * 8)) | (0xFFu << (g2 * 8));  // allowed experts
        int topi[NTOPK]; unsigned used = 0;
        for (int k = 0; k < NTOPK; ++k) {         // top-8 by sb among allowed
            int best = -1; float bv = -1e30f;
            for (int e = 0; e < NE; ++e) {
                if (!((am >> e) & 1) || ((used >> e) & 1)) continue;
                if (sb[e] > bv) { bv = sb[e]; best = e; }
            }
            used |= 1u << best; topi[k] = best;
        }
        float wsum = 0.f;
        for (int k = 0; k < NTOPK; ++k) wsum += sc[topi[k]];
        float inv = RSCALE / wsum;
        for (int k = 0; k < NTOPK; ++k) {
            int e = topi[k];
            int pos = atomicAdd(&counts[e], 1);
            tl_tok[e * TTOK + pos] = t | (k << 16);
            tl_w[e * TTOK + pos] = sc[e] * inv;
        }
    }
}

__global__ void scan_offsets(const int* __restrict__ counts, int* __restrict__ offsets) {
    if (threadIdx.x == 0) {
        int a = 0;
        for (int e = 0; e < NE; ++e) { offsets[e] = a; a += counts[e]; }
    }
}

// gather x_lat rows into expert-sorted xlp; record per-row weight and t->row map
__global__ __launch_bounds__(256) void gather_rows(const unsigned short* __restrict__ xlatb,
                                                   const int* __restrict__ counts,
                                                   const int* __restrict__ offsets,
                                                   const int* __restrict__ tl_tok,
                                                   const float* __restrict__ tl_w,
                                                   unsigned short* __restrict__ xlp,
                                                   float* __restrict__ row_w,
                                                   int* __restrict__ row_of) {
    int e = blockIdx.y;
    int cnt = counts[e], off = offsets[e];
    int pos0 = blockIdx.x * 8;
    if (pos0 >= cnt) return;
    for (int i = 0; i < 8; ++i) {
        int pos = pos0 + i;
        if (pos >= cnt) break;
        int r = off + pos;
        int ent = tl_tok[e * TTOK + pos];
        int t = ent & 0xFFFF, k = ent >> 16;
        if (threadIdx.x == 0) { row_w[r] = tl_w[e * TTOK + pos]; row_of[t * 8 + k] = r; }
        ((uint2*)(xlp + (size_t)r * LATD))[threadIdx.x] =
            ((const uint2*)(xlatb + (size_t)t * LATD))[threadIdx.x];
    }
}

// sum the 8 per-slot partial y_lat rows of each token -> bf16 y_lat
__global__ __launch_bounds__(256) void reduce_ylat(const unsigned short* __restrict__ yp,
                                                   const int* __restrict__ row_of,
                                                   unsigned short* __restrict__ yl) {
    int t = blockIdx.x;
    int r[8];
    #pragma unroll
    for (int k = 0; k < 8; ++k) r[k] = row_of[t * 8 + k];
    int c4 = threadIdx.x;  // 4 bf16 per thread
    float s0 = 0, s1 = 0, s2 = 0, s3 = 0;
    #pragma unroll
    for (int k = 0; k < 8; ++k) {
        ushort4 v = ((const ushort4*)(yp + (size_t)r[k] * LATD))[c4];
        s0 += b2f(v.x); s1 += b2f(v.y); s2 += b2f(v.z); s3 += b2f(v.w);
    }
    ushort4 ov; ov.x = f2b(s0); ov.y = f2b(s1); ov.z = f2b(s2); ov.w = f2b(s3);
    ((ushort4*)(yl + (size_t)t * LATD))[c4] = ov;
}

// ---------------- bf16 MFMA GEMM: C = A[M,K] @ B[N,K]^T ----------------
// m97 structure: 128x128 tile, BK=64, 4 waves (2x2), global_load_lds x16B.
// MODE: 0=store bf16, 1=relu2->bf16, 2=relu2*rowscale->bf16, 3=store f32, 4=add f32
template<int MODE, bool EXPERT>
__global__ __launch_bounds__(256) void gemm_bt(const unsigned short* __restrict__ A,
                                               const unsigned short* __restrict__ Bm,
                                               void* __restrict__ Cv,
                                               int M, int N, int K,
                                               const int* __restrict__ eoff,
                                               const int* __restrict__ ecnt,
                                               const float* __restrict__ rowscale) {
    __shared__ unsigned short As[128 * 64];
    __shared__ unsigned short Bs[128 * 64];
    int m0 = blockIdx.x * 128, n0 = blockIdx.y * 128;
    int crow0 = 0;
    if (EXPERT) {
        int e = blockIdx.z;
        int cnt = ecnt[e];
        if (m0 >= cnt) return;   // uniform per block: no barrier divergence
        crow0 = eoff[e];
        M = cnt;
        A += (size_t)crow0 * K;
        Bm += (size_t)e * (size_t)N * K;
    }
    int wid = threadIdx.x >> 6, lane = threadIdx.x & 63;
    int wm = wid >> 1, wn = wid & 1;
    int lrow = lane & 15, lkhi = lane >> 4;

    f32x4 acc[4][4];
    #pragma unroll
    for (int i = 0; i < 4; ++i)
        #pragma unroll
        for (int j = 0; j < 4; ++j) acc[i][j] = (f32x4){0.f, 0.f, 0.f, 0.f};

    for (int k0 = 0; k0 < K; k0 += 64) {
        #pragma unroll
        for (int it = 0; it < 4; ++it) {
            int j = wid * 4 + it;          // issue index 0..15
            int c = j * 64 + lane;         // 16B chunk id within 128x64 tile
            int row = c >> 3, col = (c & 7) << 3;
            int gr = m0 + row;
            if (EXPERT && gr >= M) gr = M - 1;  // clamp tail rows (valid addr)
            __builtin_amdgcn_global_load_lds((GVoid*)(A + (size_t)gr * K + k0 + col),
                                             (LVoid*)(As + j * 512), 16, 0, 0);
            int gn = n0 + row;
            __builtin_amdgcn_global_load_lds((GVoid*)(Bm + (size_t)gn * K + k0 + col),
                                             (LVoid*)(Bs + j * 512), 16, 0, 0);
        }
        __syncthreads();   // drains vmcnt for global_load_lds
        #pragma unroll
        for (int ks = 0; ks < 2; ++ks) {
            bf16x8 a[4], b[4];
            #pragma unroll
            for (int mi = 0; mi < 4; ++mi)
                a[mi] = *(const bf16x8*)&As[(wm * 64 + mi * 16 + lrow) * 64 + ks * 32 + lkhi * 8];
            #pragma unroll
            for (int ni = 0; ni < 4; ++ni)
                b[ni] = *(const bf16x8*)&Bs[(wn * 64 + ni * 16 + lrow) * 64 + ks * 32 + lkhi * 8];
            #pragma unroll
            for (int mi = 0; mi < 4; ++mi)
                #pragma unroll
                for (int ni = 0; ni < 4; ++ni)
                    acc[mi][ni] = __builtin_amdgcn_mfma_f32_16x16x32_bf16(a[mi], b[ni], acc[mi][ni], 0, 0, 0);
        }
        __syncthreads();
    }
    // epilogue: C/D frag mapping col=lane&15, row=(lane>>4)*4+reg  [m89/m91]
    #pragma unroll
    for (int mi = 0; mi < 4; ++mi) {
        #pragma unroll
        for (int j = 0; j < 4; ++j) {
            int lm = m0 + wm * 64 + mi * 16 + lkhi * 4 + j;
            if (lm >= M) continue;
            size_t rowg = (size_t)(crow0 + lm);
            #pragma unroll
            for (int ni = 0; ni < 4; ++ni) {
                int col = n0 + wn * 64 + ni * 16 + lrow;
                float v = acc[mi][ni][j];
                size_t idx = rowg * (size_t)N + col;
                if (MODE == 0) {
                    ((unsigned short*)Cv)[idx] = f2b(v);
                } else if (MODE == 1) {
                    v = fmaxf(v, 0.f); v *= v;
                    ((unsigned short*)Cv)[idx] = f2b(v);
                } else if (MODE == 2) {
                    v = fmaxf(v, 0.f); v = v * v * rowscale[rowg];
                    ((unsigned short*)Cv)[idx] = f2b(v);
                } else if (MODE == 3) {
                    ((float*)Cv)[idx] = v;
                } else {
                    ((float*)Cv)[idx] += v;
                }
            }
        }
    }
}

extern "C" void kernel_launch(void* const* d_in, const int* in_sizes, int n_in,
                              void* d_out, int out_size, void* d_ws, size_t ws_size,
                              hipStream_t stream) {
    const float* x   = (const float*)d_in[0];
    const float* gw  = (const float*)d_in[1];
    const float* gb  = (const float*)d_in[2];
    const float* fc1 = (const float*)d_in[3];
    const float* fc2 = (const float*)d_in[4];
    const float* w1  = (const float*)d_in[5];
    const float* w2  = (const float*)d_in[6];
    const float* sup = (const float*)d_in[7];
    const float* sdn = (const float*)d_in[8];
    float* out = (float*)d_out;

    char* ws = (char*)d_ws;
    size_t o = 0;
    auto alloc = [&](size_t b) { size_t r = o; o += (b + 255) & ~(size_t)255; return r; };

    unsigned short* xb    = (unsigned short*)(ws + alloc((size_t)TTOK * H * 2));
    unsigned short* fc1b  = (unsigned short*)(ws + alloc((size_t)LATD * H * 2));
    unsigned short* fc2b  = (unsigned short*)(ws + alloc((size_t)H * LATD * 2));
    unsigned short* w1b   = (unsigned short*)(ws + alloc((size_t)NE * INTERD * LATD * 2));
    unsigned short* w2b   = (unsigned short*)(ws + alloc((size_t)NE * LATD * INTERD * 2));
    unsigned short* supb  = (unsigned short*)(ws + alloc((size_t)SINTER * H * 2));
    unsigned short* sdnb  = (unsigned short*)(ws + alloc((size_t)H * SINTER * 2));
    unsigned short* xlatb = (unsigned short*)(ws + alloc((size_t)TTOK * LATD * 2));
    unsigned short* smid  = (unsigned short*)(ws + alloc((size_t)TTOK * SINTER * 2));
    unsigned short* xlp   = (unsigned short*)(ws + alloc((size_t)TKROWS * LATD * 2));
    unsigned short* hbuf  = (unsigned short*)(ws + alloc((size_t)TKROWS * INTERD * 2));
    unsigned short* ypart = (unsigned short*)(ws + alloc((size_t)TKROWS * LATD * 2));
    unsigned short* ylatb = (unsigned short*)(ws + alloc((size_t)TTOK * LATD * 2));
    int*   counts  = (int*)(ws + alloc(NE * 4));
    int*   offsets = (int*)(ws + alloc(NE * 4));
    int*   tl_tok  = (int*)(ws + alloc((size_t)NE * TTOK * 4));
    float* tl_w    = (float*)(ws + alloc((size_t)NE * TTOK * 4));
    float* row_w   = (float*)(ws + alloc((size_t)TKROWS * 4));
    int*   row_of  = (int*)(ws + alloc((size_t)TKROWS * 4));

    hipMemsetAsync(counts, 0, NE * 4, stream);

    auto cvt = [&](const float* src, unsigned short* dst, size_t n) {
        long n4 = (long)(n / 4);
        int blocks = (int)((n4 + 255) / 256);
        if (blocks > 4096) blocks = 4096;
        cvt_f32_bf16<<<blocks, 256, 0, stream>>>(src, dst, n4);
    };
    cvt(x,   xb,   (size_t)TTOK * H);
    cvt(fc1, fc1b, (size_t)LATD * H);
    cvt(fc2, fc2b, (size_t)H * LATD);
    cvt(w1,  w1b,  (size_t)NE * INTERD * LATD);
    cvt(w2,  w2b,  (size_t)NE * LATD * INTERD);
    cvt(sup, supb, (size_t)SINTER * H);
    cvt(sdn, sdnb, (size_t)H * SINTER);

    gate_route<<<TTOK, 256, 0, stream>>>(x, gw, gb, counts, tl_tok, tl_w);
    scan_offsets<<<1, 64, 0, stream>>>(counts, offsets);

    // x_lat = x @ fc1^T   [2048,1024] bf16
    gemm_bt<0, false><<<dim3(TTOK / 128, LATD / 128), 256, 0, stream>>>(
        xb, fc1b, xlatb, TTOK, LATD, H, nullptr, nullptr, nullptr);

    gather_rows<<<dim3(TTOK / 8, NE), 256, 0, stream>>>(
        xlatb, counts, offsets, tl_tok, tl_w, xlp, row_w, row_of);

    // shared: smid = relu2(x @ sup^T) ; out = smid @ sdn^T (f32 store)
    gemm_bt<1, false><<<dim3(TTOK / 128, SINTER / 128), 256, 0, stream>>>(
        xb, supb, smid, TTOK, SINTER, H, nullptr, nullptr, nullptr);
    gemm_bt<3, false><<<dim3(TTOK / 128, H / 128), 256, 0, stream>>>(
        smid, sdnb, out, TTOK, H, SINTER, nullptr, nullptr, nullptr);

    // routed experts (token-grouped):
    // h = relu2(xlp @ w1[e]^T) * row_w   -> hbuf
    gemm_bt<2, true><<<dim3(TTOK / 128, INTERD / 128, NE), 256, 0, stream>>>(
        xlp, w1b, hbuf, 0, INTERD, LATD, offsets, counts, row_w);
    // ypart = hbuf @ w2[e]^T
    gemm_bt<0, true><<<dim3(TTOK / 128, LATD / 128, NE), 256, 0, stream>>>(
        hbuf, w2b, ypart, 0, LATD, INTERD, offsets, counts, nullptr);

    reduce_ylat<<<TTOK, 256, 0, stream>>>(ypart, row_of, ylatb);

    // out += y_lat @ fc2^T
    gemm_bt<4, false><<<dim3(TTOK / 128, H / 128), 256, 0, stream>>>(
        ylatb, fc2b, out, TTOK, H, LATD, nullptr, nullptr, nullptr);
}

// Round 2
// 1005.341 us; speedup vs baseline: 1.2826x; 1.2826x over previous
//
#include <hip/hip_runtime.h>
#include <stdint.h>

// Problem constants (NemotronHMOE)
#define H      2048
#define LATD   1024
#define INTERD 1024
#define NE     32
#define NG     4
#define NTOPK  8
#define SINTER 4096
#define TTOK   2048          // B*S tokens
#define RSCALE 2.5f
#define TKROWS (TTOK*NTOPK)  // 16384 routed row-slots
#define MPAD_BLKS 160        // ceil((16384 + 32*127)/128)
#define MPAD_ROWS (MPAD_BLKS*128)

typedef __attribute__((ext_vector_type(8))) short bf16x8;
typedef __attribute__((ext_vector_type(4))) float f32x4;

typedef const void GVoid __attribute__((address_space(1)));
typedef void LVoid __attribute__((address_space(3)));

__device__ __forceinline__ float b2f(unsigned short u) {
    union { float f; unsigned u; } x; x.u = ((unsigned)u) << 16; return x.f;
}
__device__ __forceinline__ unsigned short f2b(float f) {  // round-to-nearest-even
    union { float f; unsigned u; } x; x.f = f;
    unsigned r = x.u + 0x7FFF + ((x.u >> 16) & 1);
    return (unsigned short)(r >> 16);
}

// ---------------- fp32 -> bf16 bulk convert ----------------
__global__ __launch_bounds__(256) void cvt_f32_bf16(const float* __restrict__ in,
                                                    unsigned short* __restrict__ out,
                                                    long n4) {
    long stride = (long)gridDim.x * 256;
    for (long i = (long)blockIdx.x * 256 + threadIdx.x; i < n4; i += stride) {
        float4 v = ((const float4*)in)[i];
        ushort4 o;
        o.x = f2b(v.x); o.y = f2b(v.y); o.z = f2b(v.z); o.w = f2b(v.w);
        ((ushort4*)out)[i] = o;
    }
}

// ---------------- gate + routing (exact fp32) ----------------
__global__ __launch_bounds__(256) void gate_route(const float* __restrict__ x,
                                                  const float* __restrict__ gw,
                                                  const float* __restrict__ gb,
                                                  int* __restrict__ counts,
                                                  int* __restrict__ tl_tok,
                                                  float* __restrict__ tl_w) {
    __shared__ float xs[H];
    __shared__ float lg[NE];
    int t = blockIdx.x;
    const float4* xp = (const float4*)(x + (size_t)t * H);
    for (int i = threadIdx.x; i < H / 4; i += 256) ((float4*)xs)[i] = xp[i];
    __syncthreads();
    int wid = threadIdx.x >> 6, lane = threadIdx.x & 63;
    #pragma unroll
    for (int ei = 0; ei < 8; ++ei) {
        int e = wid * 8 + ei;
        const float* w = gw + (size_t)e * H;
        float s = 0.f;
        for (int i = lane; i < H; i += 64) s += xs[i] * w[i];
        #pragma unroll
        for (int off = 32; off; off >>= 1) s += __shfl_xor(s, off);
        if (lane == 0) lg[e] = s;
    }
    __syncthreads();
    if (threadIdx.x == 0) {
        float sc[NE], sb[NE];
        for (int e = 0; e < NE; ++e) {
            sc[e] = 1.f / (1.f + expf(-lg[e]));   // sigmoid score
            sb[e] = sc[e] + gb[e];                // bias only affects selection
        }
        float gsc[NG];
        for (int g = 0; g < NG; ++g) {            // sum of top-2 per group
            float m1 = -1e30f, m2 = -1e30f;
            for (int i = 0; i < 8; ++i) {
                float v = sb[g * 8 + i];
                if (v > m1) { m2 = m1; m1 = v; } else if (v > m2) m2 = v;
            }
            gsc[g] = m1 + m2;
        }
        int g1 = 0;
        for (int g = 1; g < NG; ++g) if (gsc[g] > gsc[g1]) g1 = g;
        int g2 = -1;
        for (int g = 0; g < NG; ++g) { if (g == g1) continue; if (g2 < 0 || gsc[g] > gsc[g2]) g2 = g; }
        unsigned am = (0xFFu << (g1 * 8)) | (0xFFu << (g2 * 8));
        int topi[NTOPK]; unsigned used = 0;
        for (int k = 0; k < NTOPK; ++k) {
            int best = -1; float bv = -1e30f;
            for (int e = 0; e < NE; ++e) {
                if (!((am >> e) & 1) || ((used >> e) & 1)) continue;
                if (sb[e] > bv) { bv = sb[e]; best = e; }
            }
            used |= 1u << best; topi[k] = best;
        }
        float wsum = 0.f;
        for (int k = 0; k < NTOPK; ++k) wsum += sc[topi[k]];
        float inv = RSCALE / wsum;
        for (int k = 0; k < NTOPK; ++k) {
            int e = topi[k];
            int pos = atomicAdd(&counts[e], 1);
            tl_tok[e * TTOK + pos] = t | (k << 16);
            tl_w[e * TTOK + pos] = sc[e] * inv;
        }
    }
}

// padded (128-aligned) exclusive scan of counts; opad[NE] = total padded rows
__global__ void scan_offsets(const int* __restrict__ counts, int* __restrict__ opad) {
    if (threadIdx.x == 0) {
        int a = 0;
        for (int e = 0; e < NE; ++e) { opad[e] = a; a += (counts[e] + 127) & ~127; }
        opad[NE] = a;
    }
}

// per padded row: source token (rowmap), combine weight (row_w), and token-slot
// -> padded-row map (row_of). Pad rows: token 0 with weight 0.
__global__ __launch_bounds__(256) void build_rowmap(const int* __restrict__ counts,
                                                    const int* __restrict__ opad,
                                                    const int* __restrict__ tl_tok,
                                                    const float* __restrict__ tl_w,
                                                    int* __restrict__ rowmap,
                                                    float* __restrict__ row_w,
                                                    int* __restrict__ row_of) {
    int e = blockIdx.x;
    int cnt = counts[e], o0 = opad[e], o1 = opad[e + 1];
    for (int pos = threadIdx.x; pos < o1 - o0; pos += 256) {
        int r = o0 + pos;
        if (pos < cnt) {
            int ent = tl_tok[e * TTOK + pos];
            int t = ent & 0xFFFF, k = ent >> 16;
            rowmap[r] = t;
            row_w[r] = tl_w[e * TTOK + pos];
            row_of[t * 8 + k] = r;
        } else {
            rowmap[r] = 0;
            row_w[r] = 0.f;
        }
    }
}

// sum the 8 per-slot partial y_lat rows of each token -> bf16 y_lat
__global__ __launch_bounds__(256) void reduce_ylat(const unsigned short* __restrict__ yp,
                                                   const int* __restrict__ row_of,
                                                   unsigned short* __restrict__ yl) {
    int t = blockIdx.x;
    int r[8];
    #pragma unroll
    for (int k = 0; k < 8; ++k) r[k] = row_of[t * 8 + k];
    int c4 = threadIdx.x;
    float s0 = 0, s1 = 0, s2 = 0, s3 = 0;
    #pragma unroll
    for (int k = 0; k < 8; ++k) {
        ushort4 v = ((const ushort4*)(yp + (size_t)r[k] * LATD))[c4];
        s0 += b2f(v.x); s1 += b2f(v.y); s2 += b2f(v.z); s3 += b2f(v.w);
    }
    ushort4 ov; ov.x = f2b(s0); ov.y = f2b(s1); ov.z = f2b(s2); ov.w = f2b(s3);
    ((ushort4*)(yl + (size_t)t * LATD))[c4] = ov;
}

// ---------------- bf16 MFMA GEMM: C = A[M,K] @ B[N,K]^T ----------------
// 128x128 tile, BK=64, 4 waves, 2-phase double-buffered prefetch:
// next tile's global_load_lds issued BEFORE current tile's ds_read+MFMA;
// the single __syncthreads per K-step drains it after compute covers latency.
// MODE: 0=store bf16, 1=relu2->bf16, 2=relu2*rowscale->bf16, 3=store f32, 4=add f32
template<int MODE, bool EXPERT, bool INDIR>
__global__ __launch_bounds__(256) void gemm2p(const unsigned short* __restrict__ A,
                                              const unsigned short* __restrict__ Bm,
                                              void* __restrict__ Cv,
                                              int N, int K,
                                              const int* __restrict__ opad,
                                              const int* __restrict__ rowmap,
                                              const float* __restrict__ rowscale) {
    __shared__ unsigned short As[2][128 * 64];
    __shared__ unsigned short Bs[2][128 * 64];

    // bijective chunked XCD swizzle (m204), y-fastest linearization
    int GY = gridDim.y;
    int nwg = gridDim.x * GY;
    int lin = blockIdx.x * GY + blockIdx.y;
    int q = nwg >> 3, r = nwg & 7;
    int xcd = lin & 7, loc = lin >> 3;
    int swz = (xcd < r ? xcd * (q + 1) : r * (q + 1) + (xcd - r) * q) + loc;
    int m0 = (swz / GY) * 128, n0 = (swz % GY) * 128;

    if (EXPERT) {
        if (m0 >= opad[NE]) return;          // uniform: before any barrier
        int e = 0;
        while (opad[e + 1] <= m0) ++e;       // <=32 iters, uniform
        Bm += (size_t)e * (size_t)N * K;
    }

    int wid = threadIdx.x >> 6, lane = threadIdx.x & 63;
    int wm = wid >> 1, wn = wid & 1;
    int lrow = lane & 15, lkhi = lane >> 4;

    // per-lane source offsets for the 4 staged chunks (row, col fixed per lane)
    size_t aoff[4], boff[4];
    #pragma unroll
    for (int it = 0; it < 4; ++it) {
        int j = wid * 4 + it;
        int c = j * 64 + lane;
        int row = c >> 3, col = (c & 7) << 3;
        int srow = m0 + row;
        if (INDIR) srow = rowmap[srow];      // gather token row
        aoff[it] = (size_t)srow * K + col;
        boff[it] = (size_t)(n0 + row) * K + col;
    }

    f32x4 acc[4][4];
    #pragma unroll
    for (int i = 0; i < 4; ++i)
        #pragma unroll
        for (int j = 0; j < 4; ++j) acc[i][j] = (f32x4){0.f, 0.f, 0.f, 0.f};

    #define STAGE(buf, k0)                                                              \
        {                                                                               \
            _Pragma("unroll")                                                           \
            for (int it = 0; it < 4; ++it) {                                            \
                int j = wid * 4 + it;                                                   \
                __builtin_amdgcn_global_load_lds((GVoid*)(A + aoff[it] + (k0)),         \
                                                 (LVoid*)(As[buf] + j * 512), 16, 0, 0);\
                __builtin_amdgcn_global_load_lds((GVoid*)(Bm + boff[it] + (k0)),        \
                                                 (LVoid*)(Bs[buf] + j * 512), 16, 0, 0);\
            }                                                                           \
        }

    STAGE(0, 0)
    __syncthreads();

    int nt = K / 64;
    int cur = 0;
    for (int t = 0; t < nt; ++t) {
        if (t + 1 < nt) STAGE(cur ^ 1, (t + 1) * 64)   // prefetch next tile
        #pragma unroll
        for (int ks = 0; ks < 2; ++ks) {
            bf16x8 a[4], b[4];
            #pragma unroll
            for (int mi = 0; mi < 4; ++mi)
                a[mi] = *(const bf16x8*)&As[cur][(wm * 64 + mi * 16 + lrow) * 64 + ks * 32 + lkhi * 8];
            #pragma unroll
            for (int ni = 0; ni < 4; ++ni)
                b[ni] = *(const bf16x8*)&Bs[cur][(wn * 64 + ni * 16 + lrow) * 64 + ks * 32 + lkhi * 8];
            #pragma unroll
            for (int mi = 0; mi < 4; ++mi)
                #pragma unroll
                for (int ni = 0; ni < 4; ++ni)
                    acc[mi][ni] = __builtin_amdgcn_mfma_f32_16x16x32_bf16(a[mi], b[ni], acc[mi][ni], 0, 0, 0);
        }
        __syncthreads();   // drains ds_reads AND the prefetch (vmcnt 0 + lgkmcnt 0)
        cur ^= 1;
    }
    #undef STAGE

    // epilogue: C/D frag mapping col=lane&15, row=(lane>>4)*4+reg  [m89/m91]
    #pragma unroll
    for (int mi = 0; mi < 4; ++mi) {
        #pragma unroll
        for (int j = 0; j < 4; ++j) {
            size_t rowg = (size_t)(m0 + wm * 64 + mi * 16 + lkhi * 4 + j);
            #pragma unroll
            for (int ni = 0; ni < 4; ++ni) {
                int col = n0 + wn * 64 + ni * 16 + lrow;
                float v = acc[mi][ni][j];
                size_t idx = rowg * (size_t)N + col;
                if (MODE == 0) {
                    ((unsigned short*)Cv)[idx] = f2b(v);
                } else if (MODE == 1) {
                    v = fmaxf(v, 0.f); v *= v;
                    ((unsigned short*)Cv)[idx] = f2b(v);
                } else if (MODE == 2) {
                    v = fmaxf(v, 0.f); v = v * v * rowscale[rowg];
                    ((unsigned short*)Cv)[idx] = f2b(v);
                } else if (MODE == 3) {
                    ((float*)Cv)[idx] = v;
                } else {
                    ((float*)Cv)[idx] += v;
                }
            }
        }
    }
}

extern "C" void kernel_launch(void* const* d_in, const int* in_sizes, int n_in,
                              void* d_out, int out_size, void* d_ws, size_t ws_size,
                              hipStream_t stream) {
    const float* x   = (const float*)d_in[0];
    const float* gw  = (const float*)d_in[1];
    const float* gb  = (const float*)d_in[2];
    const float* fc1 = (const float*)d_in[3];
    const float* fc2 = (const float*)d_in[4];
    const float* w1  = (const float*)d_in[5];
    const float* w2  = (const float*)d_in[6];
    const float* sup = (const float*)d_in[7];
    const float* sdn = (const float*)d_in[8];
    float* out = (float*)d_out;

    char* ws = (char*)d_ws;
    size_t o = 0;
    auto alloc = [&](size_t b) { size_t r = o; o += (b + 255) & ~(size_t)255; return r; };

    unsigned short* xb    = (unsigned short*)(ws + alloc((size_t)TTOK * H * 2));
    unsigned short* fc1b  = (unsigned short*)(ws + alloc((size_t)LATD * H * 2));
    unsigned short* fc2b  = (unsigned short*)(ws + alloc((size_t)H * LATD * 2));
    unsigned short* w1b   = (unsigned short*)(ws + alloc((size_t)NE * INTERD * LATD * 2));
    unsigned short* w2b   = (unsigned short*)(ws + alloc((size_t)NE * LATD * INTERD * 2));
    unsigned short* supb  = (unsigned short*)(ws + alloc((size_t)SINTER * H * 2));
    unsigned short* sdnb  = (unsigned short*)(ws + alloc((size_t)H * SINTER * 2));
    unsigned short* xlatb = (unsigned short*)(ws + alloc((size_t)TTOK * LATD * 2));
    unsigned short* smid  = (unsigned short*)(ws + alloc((size_t)TTOK * SINTER * 2));
    unsigned short* hbuf  = (unsigned short*)(ws + alloc((size_t)MPAD_ROWS * INTERD * 2));
    unsigned short* ypart = (unsigned short*)(ws + alloc((size_t)MPAD_ROWS * LATD * 2));
    unsigned short* ylatb = (unsigned short*)(ws + alloc((size_t)TTOK * LATD * 2));
    int*   counts  = (int*)(ws + alloc(NE * 4));
    int*   opad    = (int*)(ws + alloc((NE + 1) * 4));
    int*   tl_tok  = (int*)(ws + alloc((size_t)NE * TTOK * 4));
    float* tl_w    = (float*)(ws + alloc((size_t)NE * TTOK * 4));
    int*   rowmap  = (int*)(ws + alloc((size_t)MPAD_ROWS * 4));
    float* row_w   = (float*)(ws + alloc((size_t)MPAD_ROWS * 4));
    int*   row_of  = (int*)(ws + alloc((size_t)TKROWS * 4));

    hipMemsetAsync(counts, 0, NE * 4, stream);

    auto cvt = [&](const float* src, unsigned short* dst, size_t n) {
        long n4 = (long)(n / 4);
        int blocks = (int)((n4 + 255) / 256);
        if (blocks > 4096) blocks = 4096;
        cvt_f32_bf16<<<blocks, 256, 0, stream>>>(src, dst, n4);
    };
    cvt(x,   xb,   (size_t)TTOK * H);
    cvt(fc1, fc1b, (size_t)LATD * H);
    cvt(fc2, fc2b, (size_t)H * LATD);
    cvt(w1,  w1b,  (size_t)NE * INTERD * LATD);
    cvt(w2,  w2b,  (size_t)NE * LATD * INTERD);
    cvt(sup, supb, (size_t)SINTER * H);
    cvt(sdn, sdnb, (size_t)H * SINTER);

    gate_route<<<TTOK, 256, 0, stream>>>(x, gw, gb, counts, tl_tok, tl_w);
    scan_offsets<<<1, 64, 0, stream>>>(counts, opad);
    build_rowmap<<<NE, 256, 0, stream>>>(counts, opad, tl_tok, tl_w, rowmap, row_w, row_of);

    // x_lat = x @ fc1^T   [2048,1024] bf16
    gemm2p<0, false, false><<<dim3(TTOK / 128, LATD / 128), 256, 0, stream>>>(
        xb, fc1b, xlatb, LATD, H, nullptr, nullptr, nullptr);

    // shared: smid = relu2(x @ sup^T) ; out = smid @ sdn^T (f32 store)
    gemm2p<1, false, false><<<dim3(TTOK / 128, SINTER / 128), 256, 0, stream>>>(
        xb, supb, smid, SINTER, H, nullptr, nullptr, nullptr);
    gemm2p<3, false, false><<<dim3(TTOK / 128, H / 128), 256, 0, stream>>>(
        smid, sdnb, out, H, SINTER, nullptr, nullptr, nullptr);

    // routed experts on padded flat row space:
    // h = relu2(xlat[rowmap] @ w1[e]^T) * row_w   -> hbuf
    gemm2p<2, true, true><<<dim3(MPAD_BLKS, INTERD / 128), 256, 0, stream>>>(
        xlatb, w1b, hbuf, INTERD, LATD, opad, rowmap, row_w);
    // ypart = hbuf @ w2[e]^T
    gemm2p<0, true, false><<<dim3(MPAD_BLKS, LATD / 128), 256, 0, stream>>>(
        hbuf, w2b, ypart, LATD, INTERD, opad, nullptr, nullptr);

    reduce_ylat<<<TTOK, 256, 0, stream>>>(ypart, row_of, ylatb);

    // out += y_lat @ fc2^T
    gemm2p<4, false, false><<<dim3(TTOK / 128, H / 128), 256, 0, stream>>>(
        ylatb, fc2b, out, H, LATD, nullptr, nullptr, nullptr);
}